// Round 9
// baseline (2841.369 us; speedup 1.0000x reference)
//
#include <hip/hip_runtime.h>
#include <stdint.h>

// ---------------------------------------------------------------------------
// GenLSTM r9: r8 + XCD-local (sc0/L2) exchange with architecture-checked
// enablement and sc1 fallback at every wait.
// 256 WGs x 256 thr: WG = (jwg 0..7 gate-slice, grp 0..31 batch-32).
// Group members are bids spaced 32 apart -> same bid%8 -> same XCD under
// round-robin dispatch -> shared L2 -> sc0 exchange (~250cyc RT vs ~900).
// Safety: verdict = all-8 XCC_IDs equal (exchanged via proven sc1 path at
// t=0); fast writers dual-publish (sc0->hbuf, sc1->hbuf2); fast pollers
// alternate sc0/sc1 and demote the WG (sticky) if sc0 never arrives.
// All inline-asm loads contain their s_waitcnt in the same block.
// ---------------------------------------------------------------------------

#define NGRP 32
#define KF_X 5
#define KF_H 32
#define KF_TOT 37
#define MAIN_FRAGS (8 * 8 * KF_TOT)  // jwg * slice * kf = 2368
#define Y_FRAGS 64                   // 2 row-tiles * 32 k-frags
#define TOT_FRAGS (MAIN_FRAGS + Y_FRAGS)
#define HOFF 33554432ull
#define COFF (HOFF + 524288ull)

typedef __attribute__((ext_vector_type(8))) short short8;
typedef __attribute__((ext_vector_type(4))) float f32x4;
typedef __attribute__((ext_vector_type(16))) float f32x16;
typedef __attribute__((ext_vector_type(4))) unsigned int u32x4;

__device__ __forceinline__ unsigned short f2bf(float x) {
  unsigned int u = __float_as_uint(x);
  u += 0x7FFFu + ((u >> 16) & 1u);
  return (unsigned short)(u >> 16);
}
__device__ __forceinline__ unsigned int pk2(float a, float b) {
  return (unsigned)f2bf(a) | ((unsigned)f2bf(b) << 16);
}
// unit permutation for h k-slots: bijection [0,512) <-> (kz, hi, j)
__device__ __forceinline__ int uperm(int kz, int hi, int j) {
  return 64 * (kz >> 2) + 16 * (kz & 3) + 8 * (j >> 2) + 2 * (j & 3) + hi;
}

__global__ void prep_pack(const float* __restrict__ Wih,
                          const float* __restrict__ Whh,
                          const float* __restrict__ bih,
                          const float* __restrict__ bhh,
                          const float* __restrict__ Wout,
                          const float* __restrict__ bout,
                          unsigned short* __restrict__ pack,
                          int* __restrict__ flags, int* __restrict__ flags2) {
  int tid = blockIdx.x * blockDim.x + threadIdx.x;
  if (blockIdx.x == 0) {
    for (int i = threadIdx.x; i < NGRP * 256; i += blockDim.x) {
      flags[i] = 0;
      flags2[i] = 0;
    }
  }
  int fi = tid >> 6, l = tid & 63;
  if (fi >= TOT_FRAGS) return;
  int r = l & 31, hi = l >> 5;
  unsigned short o[8];
  if (fi < MAIN_FRAGS) {
    int jwg = fi / (8 * KF_TOT);
    int rem = fi % (8 * KF_TOT);
    int w = rem / KF_TOT, kf = rem % KF_TOT;
    int g2 = r & 3, s = r >> 3, hb = (r >> 2) & 1;
    int row = g2 * 512 + jwg * 64 + w * 8 + 2 * s + hb;  // W row (4H space)
    for (int j = 0; j < 8; ++j) {
      float v;
      if (kf < KF_X) {
        int kx = kf * 16 + 8 * hi + j;
        if (kx < 64) {
          v = Wih[row * 129 + 64 + kx];
        } else if (kx == 64) {
          v = Wih[row * 129 + 128];
        } else if (kx == 65) {  // const-1 column: fused bias
          float a = bih[row] + bhh[row];
          for (int q = 0; q < 64; ++q) a += Wih[row * 129 + q] * bout[q];
          v = a;
        } else if (kx == 66) {  // t==0 indicator: cancel Wy@b_out
          float a = 0.f;
          for (int q = 0; q < 64; ++q) a -= Wih[row * 129 + q] * bout[q];
          v = a;
        } else {
          v = 0.f;
        }
      } else {
        int kz = kf - KF_X;
        int U = uperm(kz, hi, j);
        float a = Whh[row * 512 + U];
        for (int q = 0; q < 64; ++q) a += Wih[row * 129 + q] * Wout[q * 512 + U];
        v = a;
      }
      o[j] = f2bf(v);
    }
  } else {
    int fy = fi - MAIN_FRAGS;
    int ry = fy >> 5, kz = fy & 31;
    int row = ry * 32 + r;  // W_out row
    for (int j = 0; j < 8; ++j) {
      int U = uperm(kz, hi, j);
      o[j] = f2bf(Wout[row * 512 + U]);
    }
  }
  unsigned short* dst = pack + (size_t)fi * 512 + l * 8;
  for (int j = 0; j < 8; ++j) dst[j] = o[j];
}

#define AGLD(p) \
  __hip_atomic_load((p), __ATOMIC_RELAXED, __HIP_MEMORY_SCOPE_AGENT)
#define AGST(p, v) \
  __hip_atomic_store((p), (v), __ATOMIC_RELAXED, __HIP_MEMORY_SCOPE_AGENT)

__global__ __launch_bounds__(256)
__attribute__((amdgpu_waves_per_eu(1, 1))) void lstm_main(
    const float* __restrict__ noise, const float* __restrict__ dts,
    const unsigned short* __restrict__ pack, const float* __restrict__ bout,
    unsigned short* __restrict__ hbuf, unsigned short* __restrict__ hbuf2,
    int* __restrict__ flags, int* __restrict__ flags2, int fastEnable,
    float* __restrict__ out) {
  __shared__ __align__(16) unsigned short act[KF_TOT * 512];  // 37 KB
  __shared__ __align__(16) float ybuf[4 * 64 * 17];           // 17.4 KB padded
  __shared__ int xshare[8];
  __shared__ int tripflag;
  const int tid = threadIdx.x;
  const int w = tid >> 6, l = tid & 63;
  const int r = l & 31, hi = l >> 5;
  const int bid = blockIdx.x;
  const int jwg = bid >> 5, grp = bid & 31;
  const int bat = grp * 32 + r;
  const int fbase = grp * 256;

  // prologue: publish our XCC_ID via the guaranteed sc1 path (slot +16)
  if (tid == 0) {
    unsigned xcc = __builtin_amdgcn_s_getreg((31u << 11) | 20u) & 0xFFu;
    AGST(&flags2[fbase + jwg * 32 + 16], (int)xcc + 1);
    tripflag = 0;
  }

  // zero LDS h-frags (h_{-1} = 0)
  for (int i = tid; i < (KF_H * 512) / 2; i += 256)
    ((unsigned int*)(act + KF_X * 512))[i] = 0u;

  // Weight slices 2w and 2w+1: wA + wB[0..15] in AGPRs, rest arch VGPRs.
  short8 wA[KF_TOT], wB[KF_TOT];
  {
    const unsigned short* wl =
        pack + (size_t)((jwg * 8 + 2 * w) * KF_TOT) * 512 + l * 8;
#pragma unroll
    for (int kf = 0; kf < KF_TOT; ++kf) {
      wA[kf] = *(const short8*)(wl + (size_t)kf * 512);
      asm volatile("" : "+a"(wA[kf]));
      wB[kf] = *(const short8*)(wl + (size_t)(KF_TOT + kf) * 512);
      if (kf < 16)
        asm volatile("" : "+a"(wB[kf]));
      else
        asm volatile("" : "+v"(wB[kf]));
    }
  }

  float c0[4] = {0.f, 0.f, 0.f, 0.f}, c1[4] = {0.f, 0.f, 0.f, 0.f};
  float h0[4] = {0.f, 0.f, 0.f, 0.f}, h1[4] = {0.f, 0.f, 0.f, 0.f};
  float4 bo = {0.f, 0.f, 0.f, 0.f};
  if (jwg < 2) bo = *(const float4*)(bout + 32 * jwg + 8 * w + 4 * hi);

  auto cell = [&](const f32x16& a, float* cs, float* hs) {
#pragma unroll
    for (int s = 0; s < 4; ++s) {
      float iv = a[4 * s + 0], fv = a[4 * s + 1];
      float gv = a[4 * s + 2], ov = a[4 * s + 3];
      float ig = 1.f / (1.f + __expf(-iv));
      float fg = 1.f / (1.f + __expf(-fv));
      float e2g = __expf(2.f * gv);
      float gg = 1.f - 2.f / (e2g + 1.f);
      float og = 1.f / (1.f + __expf(-ov));
      float cn = fg * cs[s] + ig * gg;
      float e2c = __expf(2.f * cn);
      float tc = 1.f - 2.f / (e2c + 1.f);
      cs[s] = cn;
      hs[s] = og * tc;
    }
  };

  auto y_partial = [&]() {  // jwg<2, all 4 waves: kf slice w*8..w*8+7
    const unsigned short* yl =
        pack + (size_t)(MAIN_FRAGS + jwg * 32 + w * 8) * 512 + l * 8;
    f32x16 ya;
#pragma unroll
    for (int i = 0; i < 16; ++i) ya[i] = 0.f;
    short8 ywr[4];
#pragma unroll
    for (int p = 0; p < 4; ++p) ywr[p] = *(const short8*)(yl + (size_t)p * 512);
#pragma unroll
    for (int q = 0; q < 8; ++q) {
      short8 bv = *(const short8*)&act[(KF_X + w * 8 + q) * 512 + l * 8];
      ya = __builtin_amdgcn_mfma_f32_32x32x16_bf16(ywr[q & 3], bv, ya, 0, 0, 0);
      if (q + 4 < 8)
        ywr[q & 3] = *(const short8*)(yl + (size_t)(q + 4) * 512);
    }
#pragma unroll
    for (int s = 0; s < 4; ++s) {
      f32x4 v = {ya[4 * s], ya[4 * s + 1], ya[4 * s + 2], ya[4 * s + 3]};
      *(f32x4*)&ybuf[(w * 64 + l) * 17 + 4 * s] = v;
    }
  };

  auto y_sum = [&](int tw) {  // jwg<2, all 4 waves: q-slice 4w..4w+3
    f32x4 s0 = *(f32x4*)&ybuf[(0 * 64 + l) * 17 + 4 * w];
    f32x4 s1 = *(f32x4*)&ybuf[(1 * 64 + l) * 17 + 4 * w];
    f32x4 s2 = *(f32x4*)&ybuf[(2 * 64 + l) * 17 + 4 * w];
    f32x4 s3 = *(f32x4*)&ybuf[(3 * 64 + l) * 17 + 4 * w];
    float4 o;
    o.x = s0[0] + s1[0] + s2[0] + s3[0] + bo.x;
    o.y = s0[1] + s1[1] + s2[1] + s3[1] + bo.y;
    o.z = s0[2] + s1[2] + s2[2] + s3[2] + bo.z;
    o.w = s0[3] + s1[3] + s2[3] + s3[3] + bo.w;
    *(float4*)(out + ((size_t)bat * 512 + tw) * 64 + 32 * jwg + 8 * w +
               4 * hi) = o;
  };

  // prologue: stage x(0) (t0 indicator = 1)
  {
    const float* np = noise + (size_t)bat * 512 * 64 + w * 16 + 8 * hi;
    float4 f0 = *(const float4*)np;
    float4 f1 = *(const float4*)(np + 4);
    u32x4 d;
    d[0] = pk2(f0.x, f0.y);
    d[1] = pk2(f0.z, f0.w);
    d[2] = pk2(f1.x, f1.y);
    d[3] = pk2(f1.z, f1.w);
    *(u32x4*)&act[w * 512 + l * 8] = d;
    if (w == 0) {
      u32x4 d4 = {0u, 0u, 0u, 0u};
      if (hi == 0) {
        float dt = dts[(size_t)bat * 512];
        d4[0] = pk2(dt, 1.0f);
        d4[1] = pk2(1.0f, 0.0f);  // t==0 indicator
      }
      *(u32x4*)&act[4 * 512 + l * 8] = d4;
    }
  }
  __syncthreads();

  const int kz_own = 4 * jwg + w;
  bool fast_ok = false;
  int verdictNew = 0;

#pragma unroll 1
  for (int t = 0; t < 512; ++t) {
    const int par = t & 1;

    // A: prefetch x(t+1) into regs
    float4 nf0, nf1;
    float dtv = 0.f;
    if (t < 511) {
      const float* np =
          noise + ((size_t)bat * 512 + t + 1) * 64 + w * 16 + 8 * hi;
      nf0 = *(const float4*)np;
      nf1 = *(const float4*)(np + 4);
      if (w == 0 && hi == 0) dtv = dts[(size_t)bat * 512 + t + 1];
    }

    // B: GEMM — 37 shared B-frags feed 2 MFMAs each (tiles 2w, 2w+1)
    f32x16 a0, a1;
#pragma unroll
    for (int i = 0; i < 16; ++i) {
      a0[i] = 0.f;
      a1[i] = 0.f;
    }
#pragma unroll
    for (int kf = 0; kf < KF_TOT; ++kf) {
      short8 bv = *(const short8*)&act[kf * 512 + l * 8];
      a0 = __builtin_amdgcn_mfma_f32_32x32x16_bf16(wA[kf], bv, a0, 0, 0, 0);
      a1 = __builtin_amdgcn_mfma_f32_32x32x16_bf16(wB[kf], bv, a1, 0, 0, 0);
    }

    // D: in-lane LSTM cells
    cell(a0, c0, h0);
    cell(a1, c1, h1);

    // E: publish 16B lane slot — always sc1 copy (hbuf2); +sc0 copy if fast
    unsigned int p0 = pk2(h0[0], h0[1]), p1 = pk2(h0[2], h0[3]);
    unsigned int p2 = pk2(h1[0], h1[1]), p3 = pk2(h1[2], h1[3]);
    {
      unsigned long long* hp = (unsigned long long*)(
          hbuf2 + ((size_t)(grp * 2 + par) * KF_H + kz_own) * 512 + l * 8);
      AGST(hp, (unsigned long long)p0 | ((unsigned long long)p1 << 32));
      AGST(hp + 1, (unsigned long long)p2 | ((unsigned long long)p3 << 32));
      if (fast_ok) {
        u32x4 pay;
        pay[0] = p0;
        pay[1] = p1;
        pay[2] = p2;
        pay[3] = p3;
        unsigned long long wa =
            (unsigned long long)hbuf + (unsigned long long)(grp * 2 + par) * 32768ull +
            (unsigned long long)kz_own * 1024ull + (unsigned long long)l * 16ull;
        asm volatile("global_store_dwordx4 %0, %1, off sc0" ::"v"(wa), "v"(pay)
                     : "memory");
      }
    }

    if (jwg < 2 && t > 0) y_partial();  // y_{t-1} from h_{t-1} in act

    asm volatile("s_waitcnt vmcnt(0)" ::: "memory");  // drain ALL publishes
    __syncthreads();                                  // B2

    if (tid == 0) {
      AGST(&flags2[fbase + jwg * 32], t + 1);
      if (fast_ok) {
        unsigned long long fa = (unsigned long long)&flags[fbase + jwg * 32];
        unsigned tg = (unsigned)(t + 1);
        asm volatile("global_store_dword %0, %1, off sc0" ::"v"(fa), "v"(tg)
                     : "memory");
      }
    }

    if (jwg < 2 && t > 0) y_sum(t - 1);

    // H: stage x(t+1) from prefetched regs
    if (t < 511) {
      u32x4 d;
      d[0] = pk2(nf0.x, nf0.y);
      d[1] = pk2(nf0.z, nf0.w);
      d[2] = pk2(nf1.x, nf1.y);
      d[3] = pk2(nf1.z, nf1.w);
      *(u32x4*)&act[w * 512 + l * 8] = d;
      if (w == 0) {
        u32x4 d4 = {0u, 0u, 0u, 0u};
        if (hi == 0) d4[0] = pk2(dtv, 1.0f);
        *(u32x4*)&act[4 * 512 + l * 8] = d4;
      }
    }

    // poll
    if (fast_ok) {
      if (tid < 8) {
        unsigned long long fa = (unsigned long long)&flags[fbase + tid * 32];
        const int* f2p = &flags2[fbase + tid * 32];
        while (1) {
          unsigned v;
          asm volatile(
              "global_load_dword %0, %1, off sc0\n\ts_waitcnt vmcnt(0)"
              : "=v"(v)
              : "v"(fa)
              : "memory");
          if ((int)v >= t + 1) break;
          if (AGLD(f2p) >= t + 1) {
            tripflag = 1;  // sc1 arrived but sc0 didn't: demote WG
            break;
          }
        }
      }
    } else {
      if (tid < 8) {
        while (AGLD(&flags2[fbase + tid * 32]) < t + 1)
          __builtin_amdgcn_s_sleep(1);
        if (t == 0) xshare[tid] = AGLD(&flags2[fbase + tid * 32 + 16]);
      }
    }
    __syncthreads();  // B3

    const int tripped = tripflag;
    if (t == 0) {
      int v0 = xshare[0];
      int eq = (v0 != 0);
#pragma unroll
      for (int i = 1; i < 8; ++i) eq &= (xshare[i] == v0);
      verdictNew = (fastEnable != 0) && eq;
    }

    // refill all 32 h-frags
    if (fast_ok && !tripped) {
      unsigned long long rb =
          (unsigned long long)hbuf + (unsigned long long)(grp * 2 + par) * 32768ull +
          (unsigned long long)w * 1024ull + (unsigned long long)l * 16ull;
      u32x4 r0, r1, r2, r3, r4, r5, r6, r7;
      asm volatile(
          "global_load_dwordx4 %0, %4, off sc0\n\t"
          "global_load_dwordx4 %1, %5, off sc0\n\t"
          "global_load_dwordx4 %2, %6, off sc0\n\t"
          "global_load_dwordx4 %3, %7, off sc0\n\t"
          "s_waitcnt vmcnt(0)"
          : "=&v"(r0), "=&v"(r1), "=&v"(r2), "=&v"(r3)
          : "v"(rb), "v"(rb + 4096ull), "v"(rb + 8192ull), "v"(rb + 12288ull)
          : "memory");
      *(u32x4*)&act[(KF_X + 0 + w) * 512 + l * 8] = r0;
      *(u32x4*)&act[(KF_X + 4 + w) * 512 + l * 8] = r1;
      *(u32x4*)&act[(KF_X + 8 + w) * 512 + l * 8] = r2;
      *(u32x4*)&act[(KF_X + 12 + w) * 512 + l * 8] = r3;
      asm volatile(
          "global_load_dwordx4 %0, %4, off sc0\n\t"
          "global_load_dwordx4 %1, %5, off sc0\n\t"
          "global_load_dwordx4 %2, %6, off sc0\n\t"
          "global_load_dwordx4 %3, %7, off sc0\n\t"
          "s_waitcnt vmcnt(0)"
          : "=&v"(r4), "=&v"(r5), "=&v"(r6), "=&v"(r7)
          : "v"(rb + 16384ull), "v"(rb + 20480ull), "v"(rb + 24576ull),
            "v"(rb + 28672ull)
          : "memory");
      *(u32x4*)&act[(KF_X + 16 + w) * 512 + l * 8] = r4;
      *(u32x4*)&act[(KF_X + 20 + w) * 512 + l * 8] = r5;
      *(u32x4*)&act[(KF_X + 24 + w) * 512 + l * 8] = r6;
      *(u32x4*)&act[(KF_X + 28 + w) * 512 + l * 8] = r7;
    } else {
      const unsigned long long* src = (const unsigned long long*)(
          hbuf2 + (size_t)(grp * 2 + par) * KF_H * 512);
      unsigned long long q[16];
#pragma unroll
      for (int k = 0; k < 8; ++k) {
        int idx = (4 * k + w) * 128 + l * 2;
        q[2 * k] = AGLD(src + idx);
        q[2 * k + 1] = AGLD(src + idx + 1);
      }
#pragma unroll
      for (int k = 0; k < 8; ++k) {
        u32x4 d;
        d[0] = (unsigned)q[2 * k];
        d[1] = (unsigned)(q[2 * k] >> 32);
        d[2] = (unsigned)q[2 * k + 1];
        d[3] = (unsigned)(q[2 * k + 1] >> 32);
        *(u32x4*)&act[(KF_X + 4 * k + w) * 512 + l * 8] = d;
      }
    }
    if (tid == 0) tripflag = 0;  // reset for next step (read after next B3)
    __syncthreads();             // B1: act ready for next step

    if (tripped) fast_ok = false;          // sticky demotion
    if (t == 0) fast_ok = (verdictNew != 0);
  }

  // epilogue: y_511 + final h,c
  if (jwg < 2) y_partial();
  __syncthreads();
  if (jwg < 2) y_sum(511);
#pragma unroll
  for (int s = 0; s < 4; ++s) {
    int U0 = jwg * 64 + (2 * w + 0) * 8 + 2 * s + hi;
    int U1 = jwg * 64 + (2 * w + 1) * 8 + 2 * s + hi;
    out[HOFF + (size_t)bat * 512 + U0] = h0[s];
    out[COFF + (size_t)bat * 512 + U0] = c0[s];
    out[HOFF + (size_t)bat * 512 + U1] = h1[s];
    out[COFF + (size_t)bat * 512 + U1] = c1[s];
  }
}

extern "C" void kernel_launch(void* const* d_in, const int* in_sizes, int n_in,
                              void* d_out, int out_size, void* d_ws,
                              size_t ws_size, hipStream_t stream) {
  (void)in_sizes;
  (void)n_in;
  (void)out_size;
  const float* noise = (const float*)d_in[0];
  const float* dts = (const float*)d_in[1];
  const float* Wih = (const float*)d_in[2];
  const float* Whh = (const float*)d_in[3];
  const float* bih = (const float*)d_in[4];
  const float* bhh = (const float*)d_in[5];
  const float* Wout = (const float*)d_in[6];
  const float* bout = (const float*)d_in[7];

  unsigned short* pack = (unsigned short*)d_ws;            // 2.49 MB
  unsigned short* hbuf = pack + (size_t)TOT_FRAGS * 512;   // 2.00 MB (sc0/L2)
  unsigned short* hbuf2;
  int *flags, *flags2;
  int fastEnable;
  const size_t need = 2490368ull + 2097152ull * 2 + 65536ull;
  if (ws_size >= need) {
    hbuf2 = hbuf + 1048576;                 // 2.00 MB (sc1/LLC)
    flags = (int*)(hbuf2 + 1048576);        // 32 KB
    flags2 = flags + 8192;                  // 32 KB
    fastEnable = 1;
  } else {  // r8-compatible fallback layout
    hbuf2 = hbuf;
    flags = (int*)(hbuf + 1048576);
    flags2 = flags;
    fastEnable = 0;
  }

  prep_pack<<<(TOT_FRAGS * 64 + 255) / 256, 256, 0, stream>>>(
      Wih, Whh, bih, bhh, Wout, bout, pack, flags, flags2);
  lstm_main<<<256, 256, 0, stream>>>(noise, dts, pack, bout, hbuf, hbuf2,
                                     flags, flags2, fastEnable, (float*)d_out);
}